// Round 6
// baseline (629.588 us; speedup 1.0000x reference)
//
#include <hip/hip_runtime.h>

typedef __bf16 bf16;
typedef __attribute__((ext_vector_type(4))) __bf16 bf16x4;
typedef __attribute__((ext_vector_type(8))) __bf16 bf16x8;
typedef __attribute__((ext_vector_type(4))) float f32x4;

#define LSTR 40   // LDS row stride in bf16 elems (80B) -> 2-way max bank alias (free)
#define BN_EPS 1e-5f

// ---------------- prep: transpose fp32 weights -> bf16 transposed in ws; zero cnt -------
__global__ __launch_bounds__(256) void k_prep(
        const float* __restrict__ W0, const float* __restrict__ W1, const float* __restrict__ W2,
        bf16* __restrict__ Wt0, bf16* __restrict__ Wt1, bf16* __restrict__ Wt2,
        int* __restrict__ cnt, int n)
{
    int i = blockIdx.x*256 + threadIdx.x;
    const int T = 768*64 + 8192;
    if (i < 768*64)            { int k = i>>6, n_ = i&63;                  Wt0[n_*768+k] = (bf16)W0[i]; }
    else if (i < 768*64+4096)  { int j = i-768*64;      int k=j>>6,c=j&63; Wt1[c*64+k]  = (bf16)W1[j]; }
    else if (i < T)            { int j = i-768*64-4096; int k=j>>6,c=j&63; Wt2[c*64+k]  = (bf16)W2[j]; }
    int j = i - T;
    if (j >= 0 && j < n) cnt[j] = 0;      // self-loops handled inline in gat_agg
}

// ---------------- MFMA GEMM: A[M x K] @ Bt[64 x K] bf16 -> 64 cols --------------------
// MODE 0: epilogue bias+BN+ELU -> bf16 out (h).
// MODE 1: raw -> bf16 out (xw) + FUSED attention logits a_src/a_dst (H heads).
// ABF: A is bf16 (else fp32, converted in staging). Register-prefetch double buffer.
template<int MODE, bool ABF, int H>
__global__ __launch_bounds__(256) void k_gemm64(
        const void* __restrict__ Av, const bf16* __restrict__ Bt, int M, int K,
        const float* __restrict__ pb, const float* __restrict__ g, const float* __restrict__ bb,
        const float* __restrict__ mm, const float* __restrict__ vv,
        bf16* __restrict__ outB,
        float* __restrict__ a_s, float* __restrict__ a_d,
        const float* __restrict__ att_s, const float* __restrict__ att_d)
{
    __shared__ bf16 xs[64*LSTR];
    __shared__ bf16 bs[64*LSTR];
    __shared__ float sC[64], cC[64];

    int t = threadIdx.x;
    int w = t >> 6, lane = t & 63;
    int q = lane >> 4, l16 = lane & 15;
    int row0 = blockIdx.x * 64;
    int sRow = t >> 2, sK = (t & 3) * 8;

    auto loadA = [&](int k0) -> bf16x8 {
        bf16x8 xv;
        #pragma unroll
        for (int i = 0; i < 8; ++i) xv[i] = (bf16)0.f;
        int gr = row0 + sRow;
        if (gr < M) {
            if constexpr (ABF) {
                xv = *(const bf16x8*)((const bf16*)Av + (size_t)gr*K + k0 + sK);
            } else {
                const float* ap = (const float*)Av + (size_t)gr*K + k0 + sK;
                float4 f0 = *(const float4*)ap;
                float4 f1 = *(const float4*)(ap + 4);
                xv[0]=(bf16)f0.x; xv[1]=(bf16)f0.y; xv[2]=(bf16)f0.z; xv[3]=(bf16)f0.w;
                xv[4]=(bf16)f1.x; xv[5]=(bf16)f1.y; xv[6]=(bf16)f1.z; xv[7]=(bf16)f1.w;
            }
        }
        return xv;
    };
    auto loadB = [&](int k0) -> bf16x8 {
        return *(const bf16x8*)(Bt + (size_t)sRow*K + k0 + sK);
    };

    f32x4 acc[4];
    #pragma unroll
    for (int i = 0; i < 4; ++i) { acc[i][0]=0.f; acc[i][1]=0.f; acc[i][2]=0.f; acc[i][3]=0.f; }

    bf16x8 xv = loadA(0);
    bf16x8 bv = loadB(0);

    for (int k0 = 0; k0 < K; k0 += 32) {
        *(bf16x8*)(xs + sRow*LSTR + sK) = xv;
        *(bf16x8*)(bs + sRow*LSTR + sK) = bv;
        __syncthreads();
        if (k0 + 32 < K) {               // prefetch next tile during MFMA
            xv = loadA(k0 + 32);
            bv = loadB(k0 + 32);
        }
        // A frag: A[m=lane&15][k=q*8+j]; B frag: B[n=lane&15][k=q*8+j]
        bf16x8 af = *(bf16x8*)(xs + (w*16 + l16)*LSTR + q*8);
        #pragma unroll
        for (int tt = 0; tt < 4; ++tt) {
            bf16x8 bfr = *(bf16x8*)(bs + (tt*16 + l16)*LSTR + q*8);
            acc[tt] = __builtin_amdgcn_mfma_f32_16x16x32_bf16(af, bfr, acc[tt], 0, 0, 0);
        }
        __syncthreads();
    }

    if constexpr (MODE == 0) {
        if (t < 64) {
            float s = rsqrtf(vv[t] + BN_EPS) * g[t];
            sC[t] = s;
            cC[t] = (pb[t] - mm[t]) * s + bb[t];
        }
        __syncthreads();
    }

    // C/D: col = lane&15, row = q*4 + reg   [m89-verified]
    #pragma unroll
    for (int tt = 0; tt < 4; ++tt) {
        int col = tt*16 + l16;
        #pragma unroll
        for (int r = 0; r < 4; ++r) {
            int row = row0 + w*16 + q*4 + r;
            if (row < M) {
                float val = acc[tt][r];
                if constexpr (MODE == 0) {
                    val = val * sC[col] + cC[col];
                    val = val > 0.f ? val : __expf(val) - 1.f;   // ELU
                }
                outB[(size_t)row*64 + col] = (bf16)val;
            }
        }
    }

    if constexpr (MODE == 1) {
        // fused attention logits from the fp32 accumulator (pre-bf16-rounding)
        #pragma unroll
        for (int r = 0; r < 4; ++r) {
            int row = row0 + w*16 + q*4 + r;
            if constexpr (H == 1) {
                float ps = 0.f, pd = 0.f;
                #pragma unroll
                for (int tt = 0; tt < 4; ++tt) {
                    int col = tt*16 + l16;
                    ps += acc[tt][r] * att_s[col];
                    pd += acc[tt][r] * att_d[col];
                }
                #pragma unroll
                for (int off = 1; off < 16; off <<= 1) {
                    ps += __shfl_xor(ps, off);
                    pd += __shfl_xor(pd, off);
                }
                if (l16 == 0 && row < M) { a_s[row] = ps; a_d[row] = pd; }
            } else {
                float ps[4], pd[4];
                #pragma unroll
                for (int tt = 0; tt < 4; ++tt) {
                    int col = tt*16 + l16;          // head = col>>3 = 2*tt + (l16>>3)
                    ps[tt] = acc[tt][r] * att_s[col];
                    pd[tt] = acc[tt][r] * att_d[col];
                }
                #pragma unroll
                for (int off = 1; off < 8; off <<= 1) {
                    #pragma unroll
                    for (int tt = 0; tt < 4; ++tt) {
                        ps[tt] += __shfl_xor(ps[tt], off);
                        pd[tt] += __shfl_xor(pd[tt], off);
                    }
                }
                if ((l16 & 7) == 0 && row < M) {
                    int hb = l16 >> 3;
                    #pragma unroll
                    for (int tt = 0; tt < 4; ++tt) {
                        a_s[row*8 + 2*tt + hb] = ps[tt];
                        a_d[row*8 + 2*tt + hb] = pd[tt];
                    }
                }
            }
        }
    }
}

// ---------------- CSR build (edges only; self-loops inline in gat_agg) ----------------
__global__ __launch_bounds__(256) void k_count(const int* __restrict__ dst, int E, int* cnt) {
    int i = blockIdx.x*256 + threadIdx.x;
    if (i < E) atomicAdd(&cnt[dst[i]], 1);
}
__global__ __launch_bounds__(256) void k_scan_block(const int* __restrict__ cnt,
        int* __restrict__ rp, int* __restrict__ bsum, int n) {
    __shared__ int s[256];
    int t = threadIdx.x, v = blockIdx.x*256 + t;
    int x = (v < n) ? cnt[v] : 0;
    s[t] = x; __syncthreads();
    for (int off = 1; off < 256; off <<= 1) {
        int y = (t >= off) ? s[t-off] : 0;
        __syncthreads();
        s[t] += y;
        __syncthreads();
    }
    if (v < n) rp[v+1] = s[t];
    if (t == 255) bsum[blockIdx.x] = s[255];
}
__global__ __launch_bounds__(256) void k_scan_bsum(int* bsum, int nb) {
    __shared__ int s[256];
    int t = threadIdx.x;
    int x = (t < nb) ? bsum[t] : 0;
    s[t] = x; __syncthreads();
    for (int off = 1; off < 256; off <<= 1) {
        int y = (t >= off) ? s[t-off] : 0;
        __syncthreads();
        s[t] += y;
        __syncthreads();
    }
    if (t < nb) bsum[t] = s[t] - x;        // exclusive
}
__global__ __launch_bounds__(256) void k_finalize(int* __restrict__ rp, const int* __restrict__ bsum,
        const int* __restrict__ cnt, int* __restrict__ cursor, int n) {
    int v = blockIdx.x*256 + threadIdx.x;
    if (v < n) {
        int val = rp[v+1] + bsum[v >> 8];
        rp[v+1] = val;
        cursor[v] = val - cnt[v];          // = rp[v]
        if (v == 0) rp[0] = 0;
    }
}
__global__ __launch_bounds__(256) void k_scatter(const int* __restrict__ src, const int* __restrict__ dst,
        int E, int* __restrict__ cursor, int* __restrict__ in_src) {
    int i = blockIdx.x*256 + threadIdx.x;
    if (i < E) {
        int pos = atomicAdd(&cursor[dst[i]], 1);
        in_src[pos] = src[i];
    }
}

// ---------------- GAT aggregation, 4-edges-per-wave layout ------------------------------
// lane = 16*sub + j : sub in [0,4) = edge slot, j in [0,16) = feature quad (4j..4j+3).
// Virtual edge 0 = self-loop; subs stride the (deg+1)-long list by 4, x2 unrolled.
template<int H, bool CLS>
__global__ __launch_bounds__(256) void k_gat_agg(const bf16* __restrict__ xwb,
        const float* __restrict__ a_src, const float* __restrict__ a_dst,
        const int* __restrict__ rp, const int* __restrict__ in_src,
        const float* __restrict__ bias,
        const float* __restrict__ g, const float* __restrict__ bb,
        const float* __restrict__ mm, const float* __restrict__ vv,
        const bf16* __restrict__ resid, bf16* __restrict__ outB, float* __restrict__ outF,
        const float* __restrict__ clsW, const float* __restrict__ clsb, int n)
{
    int wv = (blockIdx.x*256 + threadIdx.x) >> 6;
    int lane = threadIdx.x & 63;
    if (wv >= n) return;
    int sub = lane >> 4, j = lane & 15;
    int h = (H == 8) ? (j >> 1) : 0;
    float adst = a_dst[wv*H + h];

    int beg = rp[wv];
    int cntv = rp[wv+1] - beg + 1;         // + virtual self edge at vi=0

    float acc0=0.f, acc1=0.f, acc2=0.f, acc3=0.f, den=0.f;
    int vi = sub;
    for (; vi + 4 < cntv; vi += 8) {
        int u0 = (vi == 0) ? wv : in_src[beg + vi - 1];
        int u1 = in_src[beg + vi + 3];
        float s0 = a_src[u0*H + h];
        float s1 = a_src[u1*H + h];
        bf16x4 q0 = *(const bf16x4*)(xwb + (size_t)u0*64 + 4*j);
        bf16x4 q1 = *(const bf16x4*)(xwb + (size_t)u1*64 + 4*j);
        float a0 = s0 + adst; a0 = (a0 > 0.f) ? a0 : 0.2f*a0; float e0 = __expf(a0);
        float a1 = s1 + adst; a1 = (a1 > 0.f) ? a1 : 0.2f*a1; float e1 = __expf(a1);
        acc0 += e0*(float)q0[0] + e1*(float)q1[0];
        acc1 += e0*(float)q0[1] + e1*(float)q1[1];
        acc2 += e0*(float)q0[2] + e1*(float)q1[2];
        acc3 += e0*(float)q0[3] + e1*(float)q1[3];
        den  += e0 + e1;
    }
    if (vi < cntv) {
        int u0 = (vi == 0) ? wv : in_src[beg + vi - 1];
        float s0 = a_src[u0*H + h];
        bf16x4 q0 = *(const bf16x4*)(xwb + (size_t)u0*64 + 4*j);
        float a0 = s0 + adst; a0 = (a0 > 0.f) ? a0 : 0.2f*a0; float e0 = __expf(a0);
        acc0 += e0*(float)q0[0];
        acc1 += e0*(float)q0[1];
        acc2 += e0*(float)q0[2];
        acc3 += e0*(float)q0[3];
        den  += e0;
    }
    // fold the 4 sub-partitions (lanes differing in bits 4,5)
    #pragma unroll
    for (int off = 16; off < 64; off <<= 1) {
        acc0 += __shfl_xor(acc0, off);
        acc1 += __shfl_xor(acc1, off);
        acc2 += __shfl_xor(acc2, off);
        acc3 += __shfl_xor(acc3, off);
        den  += __shfl_xor(den,  off);
    }

    // epilogue on features c = 4j..4j+3 (identical in all subs)
    int c0 = 4*j;
    bf16x4 rq = *(const bf16x4*)(resid + (size_t)wv*64 + c0);
    float val[4] = {acc0, acc1, acc2, acc3};
    #pragma unroll
    for (int i = 0; i < 4; ++i) {
        int c = c0 + i;
        float sc = rsqrtf(vv[c] + BN_EPS) * g[c];
        float v = val[i]/den + bias[c];
        v = (v - mm[c]) * sc + bb[c];
        v += (float)rq[i];
        val[i] = (v > 0.f) ? v : __expf(v) - 1.f;   // ELU
    }

    if constexpr (!CLS) {
        if (sub == 0) {
            bf16x4 ov;
            #pragma unroll
            for (int i = 0; i < 4; ++i) ov[i] = (bf16)val[i];
            *(bf16x4*)(outB + (size_t)wv*64 + c0) = ov;
        }
    } else {
        // fused classifier: out[wv,o] = sum_c val_c W[c,o] + b[o]
        float keep = 0.f;
        #pragma unroll
        for (int o = 0; o < 8; ++o) {
            float p = 0.f;
            #pragma unroll
            for (int i = 0; i < 4; ++i) p += val[i] * clsW[(c0+i)*8 + o];
            #pragma unroll
            for (int off = 1; off < 16; off <<= 1) p += __shfl_xor(p, off);
            if (j == o) keep = p + clsb[o];
        }
        if (sub == 0 && j < 8) outF[(size_t)wv*8 + j] = keep;
    }
}

// ---------------- host ----------------
extern "C" void kernel_launch(void* const* d_in, const int* in_sizes, int n_in,
                              void* d_out, int out_size, void* d_ws, size_t ws_size,
                              hipStream_t stream)
{
    const float* x      = (const float*)d_in[0];
    const int*   ei     = (const int*)  d_in[1];
    const float* proj_W = (const float*)d_in[2];
    const float* proj_b = (const float*)d_in[3];
    const float* bn1_g  = (const float*)d_in[4];
    const float* bn1_b  = (const float*)d_in[5];
    const float* bn1_m  = (const float*)d_in[6];
    const float* bn1_v  = (const float*)d_in[7];
    const float* bn2_g  = (const float*)d_in[8];
    const float* bn2_b  = (const float*)d_in[9];
    const float* bn2_m  = (const float*)d_in[10];
    const float* bn2_v  = (const float*)d_in[11];
    const float* bn3_g  = (const float*)d_in[12];
    const float* bn3_b  = (const float*)d_in[13];
    const float* bn3_m  = (const float*)d_in[14];
    const float* bn3_v  = (const float*)d_in[15];
    const float* W1     = (const float*)d_in[16];
    const float* att_s1 = (const float*)d_in[17];
    const float* att_d1 = (const float*)d_in[18];
    const float* b1     = (const float*)d_in[19];
    const float* W2     = (const float*)d_in[20];
    const float* att_s2 = (const float*)d_in[21];
    const float* att_d2 = (const float*)d_in[22];
    const float* b2     = (const float*)d_in[23];
    const float* cls_W  = (const float*)d_in[24];
    const float* cls_b  = (const float*)d_in[25];

    const int N = in_sizes[0] / 768;
    const int E = in_sizes[1] / 2;
    const int* srce = ei;
    const int* dste = ei + E;

    // workspace carve
    char* p = (char*)d_ws;
    auto carve = [&](size_t bytes) -> void* {
        void* r = (void*)p;
        p += (bytes + 255) & ~(size_t)255;
        return r;
    };
    bf16*  Wt0    = (bf16*) carve((size_t)64*768*2);
    bf16*  Wt1    = (bf16*) carve((size_t)64*64*2);
    bf16*  Wt2    = (bf16*) carve((size_t)64*64*2);
    bf16*  h0b    = (bf16*) carve((size_t)N*64*2);
    bf16*  h1b    = (bf16*) carve((size_t)N*64*2);
    bf16*  xwb    = (bf16*) carve((size_t)N*64*2);
    float* a_s    = (float*)carve((size_t)N*8*4);
    float* a_d    = (float*)carve((size_t)N*8*4);
    int*   cnt    = (int*)  carve((size_t)N*4);
    int*   rp     = (int*)  carve((size_t)(N+1)*4);
    int*   cursor = (int*)  carve((size_t)N*4);
    int*   bsum   = (int*)  carve(1024);
    int*   in_src = (int*)  carve((size_t)E*4);

    const int nb = (N + 255) / 256;
    const int PREP = 768*64 + 8192;

    k_prep<<<(PREP + N + 255)/256, 256, 0, stream>>>(proj_W, W1, W2, Wt0, Wt1, Wt2, cnt, N);

    // CSR (edges only; shared by both GAT layers)
    k_count<<<(E + 255)/256, 256, 0, stream>>>(dste, E, cnt);
    k_scan_block<<<nb, 256, 0, stream>>>(cnt, rp, bsum, N);
    k_scan_bsum<<<1, 256, 0, stream>>>(bsum, nb);
    k_finalize<<<nb, 256, 0, stream>>>(rp, bsum, cnt, cursor, N);
    k_scatter<<<(E + 255)/256, 256, 0, stream>>>(srce, dste, E, cursor, in_src);

    // h0 = elu(bn1(x @ proj_W + proj_b))  [bf16]
    k_gemm64<0, false, 1><<<(N + 63)/64, 256, 0, stream>>>(x, Wt0, N, 768,
            proj_b, bn1_g, bn1_b, bn1_m, bn1_v, h0b, nullptr, nullptr, nullptr, nullptr);

    // ---- GAT layer 1 (H=8): xw + fused a_src/a_dst ----
    k_gemm64<1, true, 8><<<(N + 63)/64, 256, 0, stream>>>(h0b, Wt1, N, 64,
            nullptr, nullptr, nullptr, nullptr, nullptr, xwb, a_s, a_d, att_s1, att_d1);
    k_gat_agg<8, false><<<(N + 3)/4, 256, 0, stream>>>(xwb, a_s, a_d, rp, in_src,
            b1, bn2_g, bn2_b, bn2_m, bn2_v, h0b, h1b, nullptr, nullptr, nullptr, N);

    // ---- GAT layer 2 (H=1), classifier fused into epilogue ----
    k_gemm64<1, true, 1><<<(N + 63)/64, 256, 0, stream>>>(h1b, Wt2, N, 64,
            nullptr, nullptr, nullptr, nullptr, nullptr, xwb, a_s, a_d, att_s2, att_d2);
    k_gat_agg<1, true><<<(N + 3)/4, 256, 0, stream>>>(xwb, a_s, a_d, rp, in_src,
            b2, bn3_g, bn3_b, bn3_m, bn3_v, h1b, nullptr, (float*)d_out, cls_W, cls_b, N);
}

// Round 7
// 496.907 us; speedup vs baseline: 1.2670x; 1.2670x over previous
//
#include <hip/hip_runtime.h>

typedef __bf16 bf16;
typedef __attribute__((ext_vector_type(8))) __bf16 bf16x8;
typedef __attribute__((ext_vector_type(4))) float f32x4;

#define LSTR 40   // LDS row stride in bf16 elems (80B) -> 2-way max bank alias (free)
#define BN_EPS 1e-5f

// ---------------- prep: transpose fp32 weights -> bf16 transposed in ws; zero cnt -------
__global__ __launch_bounds__(256) void k_prep(
        const float* __restrict__ W0, const float* __restrict__ W1, const float* __restrict__ W2,
        bf16* __restrict__ Wt0, bf16* __restrict__ Wt1, bf16* __restrict__ Wt2,
        int* __restrict__ cnt, int n)
{
    int i = blockIdx.x*256 + threadIdx.x;
    const int T = 768*64 + 8192;
    if (i < 768*64)            { int k = i>>6, n_ = i&63;                  Wt0[n_*768+k] = (bf16)W0[i]; }
    else if (i < 768*64+4096)  { int j = i-768*64;      int k=j>>6,c=j&63; Wt1[c*64+k]  = (bf16)W1[j]; }
    else if (i < T)            { int j = i-768*64-4096; int k=j>>6,c=j&63; Wt2[c*64+k]  = (bf16)W2[j]; }
    int j = i - T;
    if (j >= 0 && j < n) cnt[j] = 0;      // self-loops handled inline in gat_agg
}

// ---------------- MFMA GEMM: A[M x K] @ Bt[64 x K] bf16 -> 64 cols --------------------
// MODE 0: epilogue bias+BN+ELU -> bf16 out (h).
// MODE 1: raw -> bf16 out (xw) + FUSED attention logits a_src/a_dst (H heads).
// ABF: A is bf16 (else fp32, converted in staging). Register-prefetch double buffer.
template<int MODE, bool ABF, int H>
__global__ __launch_bounds__(256) void k_gemm64(
        const void* __restrict__ Av, const bf16* __restrict__ Bt, int M, int K,
        const float* __restrict__ pb, const float* __restrict__ g, const float* __restrict__ bb,
        const float* __restrict__ mm, const float* __restrict__ vv,
        bf16* __restrict__ outB,
        float* __restrict__ a_s, float* __restrict__ a_d,
        const float* __restrict__ att_s, const float* __restrict__ att_d)
{
    __shared__ bf16 xs[64*LSTR];
    __shared__ bf16 bs[64*LSTR];
    __shared__ float sC[64], cC[64];

    int t = threadIdx.x;
    int w = t >> 6, lane = t & 63;
    int q = lane >> 4, l16 = lane & 15;
    int row0 = blockIdx.x * 64;
    int sRow = t >> 2, sK = (t & 3) * 8;

    auto loadA = [&](int k0) -> bf16x8 {
        bf16x8 xv;
        #pragma unroll
        for (int i = 0; i < 8; ++i) xv[i] = (bf16)0.f;
        int gr = row0 + sRow;
        if (gr < M) {
            if constexpr (ABF) {
                xv = *(const bf16x8*)((const bf16*)Av + (size_t)gr*K + k0 + sK);
            } else {
                const float* ap = (const float*)Av + (size_t)gr*K + k0 + sK;
                float4 f0 = *(const float4*)ap;
                float4 f1 = *(const float4*)(ap + 4);
                xv[0]=(bf16)f0.x; xv[1]=(bf16)f0.y; xv[2]=(bf16)f0.z; xv[3]=(bf16)f0.w;
                xv[4]=(bf16)f1.x; xv[5]=(bf16)f1.y; xv[6]=(bf16)f1.z; xv[7]=(bf16)f1.w;
            }
        }
        return xv;
    };
    auto loadB = [&](int k0) -> bf16x8 {
        return *(const bf16x8*)(Bt + (size_t)sRow*K + k0 + sK);
    };

    f32x4 acc[4];
    #pragma unroll
    for (int i = 0; i < 4; ++i) { acc[i][0]=0.f; acc[i][1]=0.f; acc[i][2]=0.f; acc[i][3]=0.f; }

    bf16x8 xv = loadA(0);
    bf16x8 bv = loadB(0);

    for (int k0 = 0; k0 < K; k0 += 32) {
        *(bf16x8*)(xs + sRow*LSTR + sK) = xv;
        *(bf16x8*)(bs + sRow*LSTR + sK) = bv;
        __syncthreads();
        if (k0 + 32 < K) {               // prefetch next tile during MFMA
            xv = loadA(k0 + 32);
            bv = loadB(k0 + 32);
        }
        // A frag: A[m=lane&15][k=q*8+j]; B frag: B[n=lane&15][k=q*8+j]
        bf16x8 af = *(bf16x8*)(xs + (w*16 + l16)*LSTR + q*8);
        #pragma unroll
        for (int tt = 0; tt < 4; ++tt) {
            bf16x8 bfr = *(bf16x8*)(bs + (tt*16 + l16)*LSTR + q*8);
            acc[tt] = __builtin_amdgcn_mfma_f32_16x16x32_bf16(af, bfr, acc[tt], 0, 0, 0);
        }
        __syncthreads();
    }

    if constexpr (MODE == 0) {
        if (t < 64) {
            float s = rsqrtf(vv[t] + BN_EPS) * g[t];
            sC[t] = s;
            cC[t] = (pb[t] - mm[t]) * s + bb[t];
        }
        __syncthreads();
    }

    // C/D: col = lane&15, row = q*4 + reg   [m89-verified]
    #pragma unroll
    for (int tt = 0; tt < 4; ++tt) {
        int col = tt*16 + l16;
        #pragma unroll
        for (int r = 0; r < 4; ++r) {
            int row = row0 + w*16 + q*4 + r;
            if (row < M) {
                float val = acc[tt][r];
                if constexpr (MODE == 0) {
                    val = val * sC[col] + cC[col];
                    val = val > 0.f ? val : __expf(val) - 1.f;   // ELU
                }
                outB[(size_t)row*64 + col] = (bf16)val;
            }
        }
    }

    if constexpr (MODE == 1) {
        // fused attention logits from the fp32 accumulator (pre-bf16-rounding)
        #pragma unroll
        for (int r = 0; r < 4; ++r) {
            int row = row0 + w*16 + q*4 + r;
            if constexpr (H == 1) {
                float ps = 0.f, pd = 0.f;
                #pragma unroll
                for (int tt = 0; tt < 4; ++tt) {
                    int col = tt*16 + l16;
                    ps += acc[tt][r] * att_s[col];
                    pd += acc[tt][r] * att_d[col];
                }
                #pragma unroll
                for (int off = 1; off < 16; off <<= 1) {
                    ps += __shfl_xor(ps, off);
                    pd += __shfl_xor(pd, off);
                }
                if (l16 == 0 && row < M) { a_s[row] = ps; a_d[row] = pd; }
            } else {
                float ps[4], pd[4];
                #pragma unroll
                for (int tt = 0; tt < 4; ++tt) {
                    int col = tt*16 + l16;          // head = col>>3 = 2*tt + (l16>>3)
                    ps[tt] = acc[tt][r] * att_s[col];
                    pd[tt] = acc[tt][r] * att_d[col];
                }
                #pragma unroll
                for (int off = 1; off < 8; off <<= 1) {
                    #pragma unroll
                    for (int tt = 0; tt < 4; ++tt) {
                        ps[tt] += __shfl_xor(ps[tt], off);
                        pd[tt] += __shfl_xor(pd[tt], off);
                    }
                }
                if ((l16 & 7) == 0 && row < M) {
                    int hb = l16 >> 3;
                    #pragma unroll
                    for (int tt = 0; tt < 4; ++tt) {
                        a_s[row*8 + 2*tt + hb] = ps[tt];
                        a_d[row*8 + 2*tt + hb] = pd[tt];
                    }
                }
            }
        }
    }
}

// ---------------- CSR build (edges only; self-loops inline in gat_agg) ----------------
__global__ __launch_bounds__(256) void k_count(const int* __restrict__ dst, int E, int* cnt) {
    int i = blockIdx.x*256 + threadIdx.x;
    if (i < E) atomicAdd(&cnt[dst[i]], 1);
}
__global__ __launch_bounds__(256) void k_scan_block(const int* __restrict__ cnt,
        int* __restrict__ rp, int* __restrict__ bsum, int n) {
    __shared__ int s[256];
    int t = threadIdx.x, v = blockIdx.x*256 + t;
    int x = (v < n) ? cnt[v] : 0;
    s[t] = x; __syncthreads();
    for (int off = 1; off < 256; off <<= 1) {
        int y = (t >= off) ? s[t-off] : 0;
        __syncthreads();
        s[t] += y;
        __syncthreads();
    }
    if (v < n) rp[v+1] = s[t];
    if (t == 255) bsum[blockIdx.x] = s[255];
}
__global__ __launch_bounds__(256) void k_scan_bsum(int* bsum, int nb) {
    __shared__ int s[256];
    int t = threadIdx.x;
    int x = (t < nb) ? bsum[t] : 0;
    s[t] = x; __syncthreads();
    for (int off = 1; off < 256; off <<= 1) {
        int y = (t >= off) ? s[t-off] : 0;
        __syncthreads();
        s[t] += y;
        __syncthreads();
    }
    if (t < nb) bsum[t] = s[t] - x;        // exclusive
}
__global__ __launch_bounds__(256) void k_finalize(int* __restrict__ rp, const int* __restrict__ bsum,
        const int* __restrict__ cnt, int* __restrict__ cursor, int n) {
    int v = blockIdx.x*256 + threadIdx.x;
    if (v < n) {
        int val = rp[v+1] + bsum[v >> 8];
        rp[v+1] = val;
        cursor[v] = val - cnt[v];          // = rp[v]
        if (v == 0) rp[0] = 0;
    }
}
__global__ __launch_bounds__(256) void k_scatter(const int* __restrict__ src, const int* __restrict__ dst,
        int E, int* __restrict__ cursor, int* __restrict__ in_src) {
    int i = blockIdx.x*256 + threadIdx.x;
    if (i < E) {
        int pos = atomicAdd(&cursor[dst[i]], 1);
        in_src[pos] = src[i];
    }
}

// ---------------- GAT aggregation + bias + BN + residual + ELU (+ fused classifier) ----------
// Self-loop contribution computed inline. Edge loop unrolled x8 (16 gathers in flight).
template<int H, bool CLS>
__global__ __launch_bounds__(256) void k_gat_agg(const bf16* __restrict__ xwb,
        const float* __restrict__ a_src, const float* __restrict__ a_dst,
        const int* __restrict__ rp, const int* __restrict__ in_src,
        const float* __restrict__ bias,
        const float* __restrict__ g, const float* __restrict__ bb,
        const float* __restrict__ mm, const float* __restrict__ vv,
        const bf16* __restrict__ resid, bf16* __restrict__ outB, float* __restrict__ outF,
        const float* __restrict__ clsW, const float* __restrict__ clsb, int n)
{
    int wv = (blockIdx.x*256 + threadIdx.x) >> 6;
    int lane = threadIdx.x & 63;
    if (wv >= n) return;
    int h = (H == 8) ? (lane >> 3) : 0;
    float adst = a_dst[wv*H + h];

    // self-loop term
    float aself = a_src[wv*H + h] + adst;
    aself = (aself > 0.f) ? aself : 0.2f*aself;
    float eself = __expf(aself);
    float acc = eself * (float)xwb[(size_t)wv*64 + lane];
    float den = eself;

    int beg = rp[wv], end = rp[wv+1];
    int e = beg;
    for (; e + 8 <= end; e += 8) {
        int u[8];
        #pragma unroll
        for (int i = 0; i < 8; ++i) u[i] = in_src[e+i];
        float s[8], xr[8];
        #pragma unroll
        for (int i = 0; i < 8; ++i) s[i] = a_src[u[i]*H + h];
        #pragma unroll
        for (int i = 0; i < 8; ++i) xr[i] = (float)xwb[(size_t)u[i]*64 + lane];
        #pragma unroll
        for (int i = 0; i < 8; ++i) {
            float a = s[i] + adst;
            a = (a > 0.f) ? a : 0.2f*a;
            float ex = __expf(a);
            acc += ex * xr[i];
            den += ex;
        }
    }
    for (; e < end; ++e) {
        int u = in_src[e];
        float al = a_src[u*H + h] + adst;
        al = (al > 0.f) ? al : 0.2f*al;
        float ex = __expf(al);
        acc += ex * (float)xwb[(size_t)u*64 + lane];
        den += ex;
    }
    float val = acc/den + bias[lane];
    float sc = rsqrtf(vv[lane] + BN_EPS) * g[lane];
    val = (val - mm[lane]) * sc + bb[lane];
    val += (float)resid[(size_t)wv*64 + lane];
    val = (val > 0.f) ? val : __expf(val) - 1.f;   // ELU

    if constexpr (!CLS) {
        outB[(size_t)wv*64 + lane] = (bf16)val;
    } else {
        // fused classifier: out[wv, o] = sum_c val_c * W[c,o] + b[o]
        float keep = 0.f;
        #pragma unroll
        for (int o = 0; o < 8; ++o) {
            float p = val * clsW[lane*8 + o];
            #pragma unroll
            for (int off = 1; off < 64; off <<= 1) p += __shfl_xor(p, off);
            if (lane == o) keep = p + clsb[o];
        }
        if (lane < 8) outF[(size_t)wv*8 + lane] = keep;
    }
}

// ---------------- host ----------------
extern "C" void kernel_launch(void* const* d_in, const int* in_sizes, int n_in,
                              void* d_out, int out_size, void* d_ws, size_t ws_size,
                              hipStream_t stream)
{
    const float* x      = (const float*)d_in[0];
    const int*   ei     = (const int*)  d_in[1];
    const float* proj_W = (const float*)d_in[2];
    const float* proj_b = (const float*)d_in[3];
    const float* bn1_g  = (const float*)d_in[4];
    const float* bn1_b  = (const float*)d_in[5];
    const float* bn1_m  = (const float*)d_in[6];
    const float* bn1_v  = (const float*)d_in[7];
    const float* bn2_g  = (const float*)d_in[8];
    const float* bn2_b  = (const float*)d_in[9];
    const float* bn2_m  = (const float*)d_in[10];
    const float* bn2_v  = (const float*)d_in[11];
    const float* bn3_g  = (const float*)d_in[12];
    const float* bn3_b  = (const float*)d_in[13];
    const float* bn3_m  = (const float*)d_in[14];
    const float* bn3_v  = (const float*)d_in[15];
    const float* W1     = (const float*)d_in[16];
    const float* att_s1 = (const float*)d_in[17];
    const float* att_d1 = (const float*)d_in[18];
    const float* b1     = (const float*)d_in[19];
    const float* W2     = (const float*)d_in[20];
    const float* att_s2 = (const float*)d_in[21];
    const float* att_d2 = (const float*)d_in[22];
    const float* b2     = (const float*)d_in[23];
    const float* cls_W  = (const float*)d_in[24];
    const float* cls_b  = (const float*)d_in[25];

    const int N = in_sizes[0] / 768;
    const int E = in_sizes[1] / 2;
    const int* srce = ei;
    const int* dste = ei + E;

    // workspace carve
    char* p = (char*)d_ws;
    auto carve = [&](size_t bytes) -> void* {
        void* r = (void*)p;
        p += (bytes + 255) & ~(size_t)255;
        return r;
    };
    bf16*  Wt0    = (bf16*) carve((size_t)64*768*2);
    bf16*  Wt1    = (bf16*) carve((size_t)64*64*2);
    bf16*  Wt2    = (bf16*) carve((size_t)64*64*2);
    bf16*  h0b    = (bf16*) carve((size_t)N*64*2);
    bf16*  h1b    = (bf16*) carve((size_t)N*64*2);
    bf16*  xwb    = (bf16*) carve((size_t)N*64*2);
    float* a_s    = (float*)carve((size_t)N*8*4);
    float* a_d    = (float*)carve((size_t)N*8*4);
    int*   cnt    = (int*)  carve((size_t)N*4);
    int*   rp     = (int*)  carve((size_t)(N+1)*4);
    int*   cursor = (int*)  carve((size_t)N*4);
    int*   bsum   = (int*)  carve(1024);
    int*   in_src = (int*)  carve((size_t)E*4);

    const int nb = (N + 255) / 256;
    const int PREP = 768*64 + 8192;

    k_prep<<<(PREP + N + 255)/256, 256, 0, stream>>>(proj_W, W1, W2, Wt0, Wt1, Wt2, cnt, N);

    // CSR (edges only; shared by both GAT layers)
    k_count<<<(E + 255)/256, 256, 0, stream>>>(dste, E, cnt);
    k_scan_block<<<nb, 256, 0, stream>>>(cnt, rp, bsum, N);
    k_scan_bsum<<<1, 256, 0, stream>>>(bsum, nb);
    k_finalize<<<nb, 256, 0, stream>>>(rp, bsum, cnt, cursor, N);
    k_scatter<<<(E + 255)/256, 256, 0, stream>>>(srce, dste, E, cursor, in_src);

    // h0 = elu(bn1(x @ proj_W + proj_b))  [bf16]
    k_gemm64<0, false, 1><<<(N + 63)/64, 256, 0, stream>>>(x, Wt0, N, 768,
            proj_b, bn1_g, bn1_b, bn1_m, bn1_v, h0b, nullptr, nullptr, nullptr, nullptr);

    // ---- GAT layer 1 (H=8): xw + fused a_src/a_dst ----
    k_gemm64<1, true, 8><<<(N + 63)/64, 256, 0, stream>>>(h0b, Wt1, N, 64,
            nullptr, nullptr, nullptr, nullptr, nullptr, xwb, a_s, a_d, att_s1, att_d1);
    k_gat_agg<8, false><<<(N + 3)/4, 256, 0, stream>>>(xwb, a_s, a_d, rp, in_src,
            b1, bn2_g, bn2_b, bn2_m, bn2_v, h0b, h1b, nullptr, nullptr, nullptr, N);

    // ---- GAT layer 2 (H=1), classifier fused into epilogue ----
    k_gemm64<1, true, 1><<<(N + 63)/64, 256, 0, stream>>>(h1b, Wt2, N, 64,
            nullptr, nullptr, nullptr, nullptr, nullptr, xwb, a_s, a_d, att_s2, att_d2);
    k_gat_agg<1, true><<<(N + 3)/4, 256, 0, stream>>>(xwb, a_s, a_d, rp, in_src,
            b2, bn3_g, bn3_b, bn3_m, bn3_v, h1b, nullptr, (float*)d_out, cls_W, cls_b, N);
}